// Round 1
// baseline (376.238 us; speedup 1.0000x reference)
//
#include <hip/hip_runtime.h>
#include <hip/hip_bf16.h>

#define SEGS 16384
#define DCH  128

using f32x4  = __attribute__((ext_vector_type(4))) float;
using bf16x8 = __attribute__((ext_vector_type(8))) short;
using u32x4  = __attribute__((ext_vector_type(4))) unsigned int;

__device__ __forceinline__ float u2f(unsigned int u) { return __uint_as_float(u); }
__device__ __forceinline__ unsigned int f2u(float f) { return __float_as_uint(f); }

// ---------------------------------------------------------------------------
// Setup: (a) convert W -> fragment-ready bf16 hi/lo B-operand layout
//        (b) per-segment row ranges via binary search on sorted index
// B[k][n] = W[n][k]; frag layout [kt][ntile][lane][8] so each lane's 8
// elements are one contiguous 16B load (lane holds B[k=(lane>>4)*8+j][n=lane&15]).
// ---------------------------------------------------------------------------
__global__ void setup_kernel(const float* __restrict__ W,
                             const int* __restrict__ index, int N,
                             unsigned short* __restrict__ WfH,
                             unsigned short* __restrict__ WfL,
                             int* __restrict__ seg_start) {
  int i = blockIdx.x * blockDim.x + threadIdx.x;
  if (i < DCH * DCH) {
    int n = i >> 7, k = i & 127;           // W[n][k]
    float w = W[i];
    unsigned int u = f2u(w);
    unsigned int hu = u & 0xFFFF0000u;     // truncated bf16 hi
    float lo = w - u2f(hu);                // residual, captured in bf16 lo
    int kt    = k >> 5;
    int ntile = n >> 4;
    int lane  = (n & 15) + 16 * ((k >> 3) & 3);
    int j     = k & 7;
    int dst = ((kt * 8 + ntile) * 64 + lane) * 8 + j;
    WfH[dst] = (unsigned short)(u >> 16);
    WfL[dst] = (unsigned short)(f2u(lo) >> 16);
  } else if (i < DCH * DCH + SEGS + 1) {
    int s = i - DCH * DCH;                 // lower_bound(index, s)
    int lo = 0, hi = N;
    while (lo < hi) {
      int mid = (lo + hi) >> 1;
      if (index[mid] < s) lo = mid + 1; else hi = mid;
    }
    seg_start[s] = lo;
  }
}

// ---------------------------------------------------------------------------
// Main: one block per segment. 4 waves; wave w owns output channels
// [32w, 32w+32). Online softmax (m, l, sum e*x) over 32-row chunks.
// att chunk computed with mfma_f32_16x16x32_bf16, 3-term hi/lo split.
// ---------------------------------------------------------------------------
__global__ __launch_bounds__(256) void pool_kernel(
    const float* __restrict__ x, const float* __restrict__ bias,
    const int* __restrict__ seg_start,
    const u32x4* __restrict__ WfH, const u32x4* __restrict__ WfL,
    float* __restrict__ out) {
  __shared__ float x_lds[32 * 132];        // pad 132 to de-conflict col reads

  const int s    = blockIdx.x;
  const int t    = threadIdx.x;
  const int wv   = t >> 6;
  const int lane = t & 63;
  const int cl   = lane & 15;              // col within 16-wide tile
  const int g    = lane >> 4;              // lane group (rows / k-group)

  const int r0  = seg_start[s];
  const int len = seg_start[s + 1] - r0;

  if (len == 0) {                          // empty segment -> zeros
    if (lane < 16) {
      out[(size_t)s * DCH + wv * 32 + cl]      = 0.f;
      out[(size_t)s * DCH + wv * 32 + 16 + cl] = 0.f;
    }
    return;
  }

  // Register-resident B fragments (this wave's 32 channels), hi & lo
  u32x4 bh[4][2], bl[4][2];
#pragma unroll
  for (int kt = 0; kt < 4; ++kt)
#pragma unroll
    for (int nt = 0; nt < 2; ++nt) {
      int off = (kt * 8 + (wv * 2 + nt)) * 64 + lane;   // 16B units
      bh[kt][nt] = WfH[off];
      bl[kt][nt] = WfL[off];
    }

  const float bcol0 = bias[wv * 32 + cl];
  const float bcol1 = bias[wv * 32 + 16 + cl];

  float m_run[2] = { -__builtin_inff(), -__builtin_inff() };
  float l_run[2] = { 0.f, 0.f };           // per-lane partial (summed over g at end)
  float a_run[2] = { 0.f, 0.f };

  for (int c0 = 0; c0 < len; c0 += 32) {
    const int rem = len - c0;
    const int mtn = (rem > 16) ? 2 : 1;

    __syncthreads();                       // protect prev-iter LDS reads
    {
      const float* src = x + (size_t)(r0 + c0) * DCH;
#pragma unroll
      for (int p = 0; p < 4; ++p) {        // coalesced: consecutive t -> consecutive 16B
        int flat = p * 1024 + t * 4;
        int row = flat >> 7, col = flat & 127;
        f32x4 v = {0.f, 0.f, 0.f, 0.f};
        if (row < rem) v = *(const f32x4*)(src + (size_t)row * DCH + col);
        *(f32x4*)&x_lds[row * 132 + col] = v;
      }
    }
    __syncthreads();

    // ---- att = x @ W^T + b for this chunk (this wave's 32 cols) ----
    f32x4 Cf[2][2];
#pragma unroll
    for (int mt = 0; mt < 2; ++mt) {
      Cf[mt][0] = (f32x4){bcol0, bcol0, bcol0, bcol0};
      Cf[mt][1] = (f32x4){bcol1, bcol1, bcol1, bcol1};
    }

#pragma unroll
    for (int kt = 0; kt < 4; ++kt) {
      u32x4 ah[2], al[2];
#pragma unroll
      for (int mt = 0; mt < 2; ++mt) {
        if (mt < mtn) {
          const float* p0 = &x_lds[(mt * 16 + cl) * 132 + kt * 32 + g * 8];
          f32x4 v0 = *(const f32x4*)p0;
          f32x4 v1 = *(const f32x4*)(p0 + 4);
          u32x4 H, L;
#pragma unroll
          for (int q = 0; q < 2; ++q) {
            f32x4 vv = q ? v1 : v0;
#pragma unroll
            for (int e = 0; e < 2; ++e) {
              unsigned int u0 = f2u(vv[e * 2]), u1 = f2u(vv[e * 2 + 1]);
              unsigned int h0 = u0 & 0xFFFF0000u, h1 = u1 & 0xFFFF0000u;
              float l0 = vv[e * 2] - u2f(h0);
              float l1 = vv[e * 2 + 1] - u2f(h1);
              H[q * 2 + e] = h1 | (u0 >> 16);
              L[q * 2 + e] = (f2u(l1) & 0xFFFF0000u) | (f2u(l0) >> 16);
            }
          }
          ah[mt] = H; al[mt] = L;
        }
      }
      // 3-split MFMA: hh, hl, lh (split-major order keeps C-chains spaced)
#pragma unroll
      for (int sp = 0; sp < 3; ++sp)
#pragma unroll
        for (int mt = 0; mt < 2; ++mt) {
          if (mt < mtn) {
#pragma unroll
            for (int nt = 0; nt < 2; ++nt) {
              bf16x8 A = __builtin_bit_cast(bf16x8, (sp == 2) ? al[mt] : ah[mt]);
              bf16x8 B = __builtin_bit_cast(bf16x8, (sp == 1) ? bl[kt][nt] : bh[kt][nt]);
              Cf[mt][nt] = __builtin_amdgcn_mfma_f32_16x16x32_bf16(A, B, Cf[mt][nt], 0, 0, 0);
            }
          }
        }
    }

    // ---- online softmax + weighted-x accumulation ----
    // C layout: col = lane&15, row(in 16-tile) = g*4 + reg   [verified m89/m91]
#pragma unroll
    for (int nt = 0; nt < 2; ++nt) {
      float vm = -__builtin_inff();
#pragma unroll
      for (int mt = 0; mt < 2; ++mt) {
        if (mt < mtn) {
#pragma unroll
          for (int r = 0; r < 4; ++r) {
            int row = mt * 16 + g * 4 + r;
            if (row < rem) vm = fmaxf(vm, Cf[mt][nt][r]);
          }
        }
      }
      vm = fmaxf(vm, __shfl_xor(vm, 16));
      vm = fmaxf(vm, __shfl_xor(vm, 32));
      float mnew = fmaxf(m_run[nt], vm);
      float sc = __expf(m_run[nt] - mnew);   // exp(-inf)=0 on first chunk
      l_run[nt] *= sc;
      a_run[nt] *= sc;
      const int cidx = wv * 32 + nt * 16 + cl;
#pragma unroll
      for (int mt = 0; mt < 2; ++mt) {
        if (mt < mtn) {
#pragma unroll
          for (int r = 0; r < 4; ++r) {
            int row = mt * 16 + g * 4 + r;
            if (row < rem) {
              float p = __expf(Cf[mt][nt][r] - mnew);
              l_run[nt] += p;
              a_run[nt] += p * x_lds[row * 132 + cidx];
            }
          }
        }
      }
      m_run[nt] = mnew;
    }
  }

  // combine the 4 lane-group partials, write
#pragma unroll
  for (int nt = 0; nt < 2; ++nt) {
    float l = l_run[nt], a = a_run[nt];
    l += __shfl_xor(l, 16); l += __shfl_xor(l, 32);
    a += __shfl_xor(a, 16); a += __shfl_xor(a, 32);
    if (lane < 16)
      out[(size_t)s * DCH + wv * 32 + nt * 16 + cl] = a / (l + 1e-16f);
  }
}

extern "C" void kernel_launch(void* const* d_in, const int* in_sizes, int n_in,
                              void* d_out, int out_size, void* d_ws, size_t ws_size,
                              hipStream_t stream) {
  const float* x    = (const float*)d_in[0];
  const float* W    = (const float*)d_in[1];
  const float* bias = (const float*)d_in[2];
  const int*   idx  = (const int*)d_in[3];
  // d_in[4] = num_segments (device scalar) — fixed at SEGS for this problem
  const int N = in_sizes[0] / DCH;

  unsigned short* WfH = (unsigned short*)d_ws;            // 32 KB
  unsigned short* WfL = WfH + DCH * DCH;                  // 32 KB
  int* seg = (int*)(WfL + DCH * DCH);                     // (SEGS+1)*4 B

  int setup_threads = DCH * DCH + SEGS + 1;
  setup_kernel<<<(setup_threads + 255) / 256, 256, 0, stream>>>(W, idx, N, WfH, WfL, seg);
  pool_kernel<<<SEGS, 256, 0, stream>>>(x, bias, seg,
                                        (const u32x4*)WfH, (const u32x4*)WfL,
                                        (float*)d_out);
}